// Round 20
// baseline (409.636 us; speedup 1.0000x reference)
//
#include <hip/hip_runtime.h>
#include <hip/hip_bf16.h>

typedef __hip_bfloat16 bf16;
typedef short v8s __attribute__((ext_vector_type(8)));     // 8 bf16 (4 VGPRs)
typedef float f32x4 __attribute__((ext_vector_type(4)));   // MFMA acc
typedef unsigned int u32x4 __attribute__((ext_vector_type(4)));

#define B_  32
#define L_  144
#define D_  96
#define HW_ 64

#define PIXSTRIDE 80             // 32 l * 2B = 64B data + 16B pad (round-7/14 layout)
#define WPACK_ELEMS (83*5*96*32) // packed bf16 weights
#define ABUF_HALF 18432          // 3 taps * 6KB A per tap

__device__ __forceinline__ unsigned short f2bf(float f) {
    union { float f; unsigned int u; } x{f};
    unsigned int r = x.u + 0x7fffu + ((x.u >> 16) & 1u);   // RNE
    return (unsigned short)(r >> 16);
}
__device__ __forceinline__ float bf2f(unsigned short u) {
    union { unsigned int u; float f; } x{(unsigned int)u << 16};
    return x.f;
}

// ---------------------------------------------------------------------------
// Weight prep, COLUMN-MAJOR tap slots (round-20): slot T holds tap
// (kh = U%KSZ, kw = U/KSZ) of its branch (U = branch-local slot), so the
// kernel's linear 3-tap DMA groups iterate kh-inner/kw-outer — enabling
// B-row sharing across the 3 taps of an in-column group.
// wpack[((T*5+q)*96 + d)*32 + l~];  T: 0..48=7x7, 49..73=5x5, 74..82=3x3.
// ---------------------------------------------------------------------------
__global__ __launch_bounds__(256) void prep_weights(
    const float* __restrict__ w1, const float* __restrict__ w2,
    const float* __restrict__ w3, unsigned short* __restrict__ wpack)
{
    int i = blockIdx.x * 256 + threadIdx.x;
    if (i >= WPACK_ELEMS) return;
    const int lt = i & 31;
    const int d  = (i >> 5) % 96;
    const int r  = (i >> 5) / 96;   // T*5 + q
    const int q  = r % 5;
    const int T  = r / 5;
    const int l  = q * 32 + lt;
    float v = 0.f;
    if (l < L_) {
        if (T < 49)      { const int U = T;      v = w3[(d * L_ + l) * 49 + (U % 7) * 7 + U / 7]; }
        else if (T < 74) { const int U = T - 49; v = w2[(d * L_ + l) * 25 + (U % 5) * 5 + U / 5]; }
        else             { const int U = T - 74; v = w1[(d * L_ + l) * 9  + (U % 3) * 3 + U / 3]; }
    }
    wpack[i] = f2bf(v);
}

// ---------------------------------------------------------------------------
// Single-branch MFMA conv — round-19 structure (12 accs, 4 waves/SIMD,
// [pixel][32ch] stride-80 patch, b128 staging, A via double-buffered
// 3-tap-group global_load_lds) + round-20 change: taps iterate COLUMN-major
// and a group whose 3 taps share a column reads 6 B-row-frags once
// (tap ti uses Bw[ti..ti+3]) instead of 12 — round-19 counters showed the
// LDS READ pipe (27.4K b128/CU ~ 330K cy) is the top consumer vs MFMA 228K.
// Spanning/tail groups use the proven round-19 per-tap body.
// MODE 0: y -> slot upper half (7x7/y3); MODE 1: y -> lower (5x5/y2);
// MODE 2: y1 + combine: add -> lower, max -> upper.
// ---------------------------------------------------------------------------
template<int KSZ, int TBASE, int MODE>
__global__ __launch_bounds__(512, 4) void conv_branch(
    const float* __restrict__ x, const unsigned short* __restrict__ wpack,
    const float* __restrict__ bb, const float* __restrict__ gg,
    const float* __restrict__ bbe, const float* __restrict__ mm,
    const float* __restrict__ vv,
    float* __restrict__ outp)
{
    constexpr int PAD  = KSZ / 2;
    constexpr int PXR  = 16 + 2 * PAD;    // patch rows/cols
    constexpr int NPIX = PXR * PXR;
    constexpr int NT   = KSZ * KSZ;       // taps
    constexpr int NG   = (NT + 2) / 3;    // 3-tap groups

    __shared__ __align__(16) unsigned char patchB[NPIX * PIXSTRIDE];
    __shared__ __align__(16) unsigned char AbufRaw[2 * ABUF_HALF];
    __shared__ float bns[96 * 2];

    const int t    = threadIdx.x;
    const int lane = t & 63;
    const int wid  = t >> 6;           // 0..7
    const int dhalf = wid >> 2;        // 0..1
    const int ptb   = (wid & 3) * 4;   // px-quad base row
    const int lo = lane & 15;
    const int hi = lane >> 4;

    const int st = blockIdx.x;
    const int h0 = (st >> 2) << 4;
    const int w0 = (st & 3) << 4;
    const int b  = blockIdx.y;

    const int laneBoff = lo * PIXSTRIDE + hi * 16;

    // staging precompute: thread owns pixel t (div/mod once)
    const bool pvalid = (t < NPIX);
    const int pr = t / PXR, pc = t - pr * PXR;
    const int gh = h0 - PAD + pr, gw = w0 - PAD + pc;
    const bool inb = pvalid && ((unsigned)gh < 64u) && ((unsigned)gw < 64u);
    const float* xb = x + (((size_t)b * L_) << 12);
    const long goff = (long)(gh << 6) + gw;

    if (t < 96) {
        const float iv = gg[t] * rsqrtf(vv[t] + 1e-5f);
        bns[t*2+0] = iv;
        bns[t*2+1] = fmaf(bb[t] - mm[t], iv, bbe[t]);
    }

    f32x4 acc[3][4];
    #pragma unroll
    for (int dt = 0; dt < 3; ++dt)
        #pragma unroll
        for (int pp = 0; pp < 4; ++pp) acc[dt][pp] = (f32x4)0.f;

    // per-lane pre-swizzled A source offset (elems): lane's frag within a 512-elem block
    const int laneAsrc = (lane & 15) * 32 + (lane >> 4) * 8;

    for (int q = 0; q < 5; ++q) {
        // ---- stage patch chunk q: 4x ds_write_b128 (8 channels each) ----
        if (pvalid) {
            if (q * 32 + 31 < L_) {            // chunks 0..3: all channels valid
                #pragma unroll
                for (int l0 = 0; l0 < 32; l0 += 8) {
                    const long gbase = (long)(q * 32 + l0) * 4096 + goff;
                    const float f0 = inb ? xb[gbase]           : 0.f;
                    const float f1 = inb ? xb[gbase + 4096]    : 0.f;
                    const float f2 = inb ? xb[gbase + 2*4096]  : 0.f;
                    const float f3 = inb ? xb[gbase + 3*4096]  : 0.f;
                    const float f4 = inb ? xb[gbase + 4*4096]  : 0.f;
                    const float f5 = inb ? xb[gbase + 5*4096]  : 0.f;
                    const float f6 = inb ? xb[gbase + 6*4096]  : 0.f;
                    const float f7 = inb ? xb[gbase + 7*4096]  : 0.f;
                    const unsigned int a0 = (unsigned int)f2bf(f0) | ((unsigned int)f2bf(f1) << 16);
                    const unsigned int a1 = (unsigned int)f2bf(f2) | ((unsigned int)f2bf(f3) << 16);
                    const unsigned int a2 = (unsigned int)f2bf(f4) | ((unsigned int)f2bf(f5) << 16);
                    const unsigned int a3 = (unsigned int)f2bf(f6) | ((unsigned int)f2bf(f7) << 16);
                    const u32x4 v = {a0, a1, a2, a3};
                    *(u32x4*)(patchB + t * PIXSTRIDE + l0 * 2) = v;
                }
            } else {                           // chunk 4: channels 128..159, guard >143
                #pragma unroll
                for (int l0 = 0; l0 < 32; l0 += 8) {
                    const int lg = q * 32 + l0;
                    const long gbase = (long)lg * 4096 + goff;
                    const float f0 = (inb && lg + 0 < L_) ? xb[gbase]          : 0.f;
                    const float f1 = (inb && lg + 1 < L_) ? xb[gbase + 4096]   : 0.f;
                    const float f2 = (inb && lg + 2 < L_) ? xb[gbase + 2*4096] : 0.f;
                    const float f3 = (inb && lg + 3 < L_) ? xb[gbase + 3*4096] : 0.f;
                    const float f4 = (inb && lg + 4 < L_) ? xb[gbase + 4*4096] : 0.f;
                    const float f5 = (inb && lg + 5 < L_) ? xb[gbase + 5*4096] : 0.f;
                    const float f6 = (inb && lg + 6 < L_) ? xb[gbase + 6*4096] : 0.f;
                    const float f7 = (inb && lg + 7 < L_) ? xb[gbase + 7*4096] : 0.f;
                    const unsigned int a0 = (unsigned int)f2bf(f0) | ((unsigned int)f2bf(f1) << 16);
                    const unsigned int a1 = (unsigned int)f2bf(f2) | ((unsigned int)f2bf(f3) << 16);
                    const unsigned int a2 = (unsigned int)f2bf(f4) | ((unsigned int)f2bf(f5) << 16);
                    const unsigned int a3 = (unsigned int)f2bf(f6) | ((unsigned int)f2bf(f7) << 16);
                    const u32x4 v = {a0, a1, a2, a3};
                    *(u32x4*)(patchB + t * PIXSTRIDE + l0 * 2) = v;
                }
            }
        }

        // ---- DMA-stage A group: chunk c = tap*6 + (dhalf*3+dt), 1KB each ----
        auto stageA = [&](int tapLo, int bufOff) {
            const int rem  = NT - tapLo;
            const int nch  = (rem < 3 ? rem : 3) * 6;
            const unsigned short* gq = wpack
                + (size_t)(TBASE + tapLo) * 15360 + (size_t)q * 3072 + laneAsrc;
            for (int c = wid; c < nch; c += 8) {
                const int tapIdx = c / 6;
                const int r = c - tapIdx * 6;
                const unsigned short* g = gq + (size_t)tapIdx * 15360 + r * 512;
                __builtin_amdgcn_global_load_lds(
                    (const __attribute__((address_space(1))) unsigned int*)g,
                    (__attribute__((address_space(3))) unsigned int*)(AbufRaw + bufOff + c * 1024),
                    16, 0, 0);
            }
        };

        stageA(0, 0);          // prologue: group 0 -> buf 0
        __syncthreads();       // patch + A group 0 visible

        for (int tg = 0; tg < NG; ++tg) {
            if (tg + 1 < NG) stageA((tg + 1) * 3, ((tg + 1) & 1) * ABUF_HALF);

            // ---- compute group tg from buf[tg&1] ----
            const unsigned char* Ab = AbufRaw + (tg & 1) * ABUF_HALF;
            const int tapLo = tg * 3;
            const int rem = NT - tapLo;
            const int ntap = rem < 3 ? rem : 3;
            const int kw0 = tapLo / KSZ;
            const int kh0 = tapLo - kw0 * KSZ;

            if (ntap == 3 && kh0 + 2 < KSZ) {
                // ---- FAST: 3 taps in column kw0, kh = kh0..kh0+2.
                // Shared B window: rows ptb+kh0 .. ptb+kh0+5 at col kw0.
                const int pix0 = (ptb + kh0) * PXR + kw0;
                v8s Bw[6];
                #pragma unroll
                for (int j = 0; j < 6; ++j)
                    Bw[j] = *(const v8s*)(patchB + (pix0 + j * PXR) * PIXSTRIDE + laneBoff);
                #pragma unroll
                for (int ti = 0; ti < 3; ++ti) {
                    const unsigned char* Abase = Ab + (ti * 6 + dhalf * 3) * 1024 + lane * 16;
                    const v8s A0 = *(const v8s*)(Abase);
                    const v8s A1 = *(const v8s*)(Abase + 1024);
                    const v8s A2 = *(const v8s*)(Abase + 2048);
                    #pragma unroll
                    for (int pp = 0; pp < 4; ++pp) {
                        acc[0][pp] = __builtin_amdgcn_mfma_f32_16x16x32_bf16(A0, Bw[ti + pp], acc[0][pp], 0, 0, 0);
                        acc[1][pp] = __builtin_amdgcn_mfma_f32_16x16x32_bf16(A1, Bw[ti + pp], acc[1][pp], 0, 0, 0);
                        acc[2][pp] = __builtin_amdgcn_mfma_f32_16x16x32_bf16(A2, Bw[ti + pp], acc[2][pp], 0, 0, 0);
                    }
                }
            } else {
                // ---- SLOW (column-spanning or tail): round-19 per-tap body.
                #pragma unroll 1
                for (int ti = 0; ti < ntap; ++ti) {
                    const int tt = tapLo + ti;
                    const int kwv = tt / KSZ;
                    const int khv = tt - kwv * KSZ;
                    const unsigned char* Abase = Ab + (ti * 6 + dhalf * 3) * 1024 + lane * 16;
                    const v8s A0 = *(const v8s*)(Abase);
                    const v8s A1 = *(const v8s*)(Abase + 1024);
                    const v8s A2 = *(const v8s*)(Abase + 2048);
                    const int rb0 = (ptb + khv) * PXR;
                    v8s Bv[4];
                    #pragma unroll
                    for (int pp = 0; pp < 4; ++pp)
                        Bv[pp] = *(const v8s*)(patchB + (rb0 + pp * PXR + kwv) * PIXSTRIDE + laneBoff);
                    #pragma unroll
                    for (int pp = 0; pp < 4; ++pp) {
                        acc[0][pp] = __builtin_amdgcn_mfma_f32_16x16x32_bf16(A0, Bv[pp], acc[0][pp], 0, 0, 0);
                        acc[1][pp] = __builtin_amdgcn_mfma_f32_16x16x32_bf16(A1, Bv[pp], acc[1][pp], 0, 0, 0);
                        acc[2][pp] = __builtin_amdgcn_mfma_f32_16x16x32_bf16(A2, Bv[pp], acc[2][pp], 0, 0, 0);
                    }
                }
            }
            __syncthreads();   // drains next group's DMA (covered by the 36 MFMAs above)
        }
    }

    // ---- epilogue (round-7/14 verbatim) ----
    #pragma unroll
    for (int dt = 0; dt < 3; ++dt) {
        #pragma unroll
        for (int reg = 0; reg < 4; ++reg) {
            const int d = dhalf * 48 + dt * 16 + hi * 4 + reg;
            const float iv = bns[d*2+0], cv = bns[d*2+1];
            unsigned short* pl = (unsigned short*)(outp + (((size_t)b * D_ + d) << 12));
            #pragma unroll
            for (int pp = 0; pp < 4; ++pp) {
                const float y = fmaxf(0.f, fmaf(acc[dt][pp][reg], iv, cv));
                const int idx = ((h0 + ptb + pp) << 6) + w0 + lo;
                if constexpr (MODE == 0) {
                    pl[4096 + idx] = f2bf(y);
                } else if constexpr (MODE == 1) {
                    pl[idx] = f2bf(y);
                } else {
                    const float y2 = bf2f(pl[idx]);
                    const float y3 = bf2f(pl[4096 + idx]);
                    const float av = y + y2 + y3;
                    const float mv = fmaxf(y, fmaxf(y2, y3));
                    pl[idx]        = f2bf(av);
                    pl[4096 + idx] = f2bf(mv);
                }
            }
        }
    }
}

// ---------------------------------------------------------------------------
// Kernel B: per-plane 3x3 conv over [add; max] with avg folded (unchanged).
// ---------------------------------------------------------------------------
__global__ __launch_bounds__(256) void fuse_kernel(
    const float* __restrict__ wf, float* __restrict__ out)
{
    const int p = blockIdx.x;      // plane = b*96 + d
    const int t = threadIdx.x;
    __shared__ float sa[66 * 66];
    __shared__ float sm[66 * 66];
    const bf16* base = (const bf16*)(out + ((size_t)p << 12));

    for (int i = t; i < 66 * 66; i += 256) {
        const int c = i % 66, r = i / 66;
        const int gh = r - 1, gw = c - 1;
        float va = 0.f, vm = 0.f;
        if (gh >= 0 && gh < 64 && gw >= 0 && gw < 64) {
            va = __bfloat162float(base[(gh << 6) + gw]);
            vm = __bfloat162float(base[4096 + (gh << 6) + gw]);
        }
        sa[i] = va; sm[i] = vm;
    }

    float wa[9], wm[9];
    #pragma unroll
    for (int j = 0; j < 9; ++j) {
        wa[j] = wf[j] + wf[9 + j] * (1.f / 3.f);
        wm[j] = wf[18 + j];
    }
    __syncthreads();

    float* op = out + ((size_t)p << 12);
    for (int i = t; i < 4096; i += 256) {
        const int h = i >> 6, w = i & 63;
        float acc = 0.f;
        #pragma unroll
        for (int kh = 0; kh < 3; ++kh) {
            #pragma unroll
            for (int kw = 0; kw < 3; ++kw) {
                acc = fmaf(sa[(h + kh) * 66 + (w + kw)], wa[kh * 3 + kw], acc);
                acc = fmaf(sm[(h + kh) * 66 + (w + kw)], wm[kh * 3 + kw], acc);
            }
        }
        op[i] = acc;
    }
}

extern "C" void kernel_launch(void* const* d_in, const int* in_sizes, int n_in,
                              void* d_out, int out_size, void* d_ws, size_t ws_size,
                              hipStream_t stream)
{
    const float* x   = (const float*)d_in[0];
    const float* w1  = (const float*)d_in[1];
    const float* b1  = (const float*)d_in[2];
    const float* g1  = (const float*)d_in[3];
    const float* be1 = (const float*)d_in[4];
    const float* m1  = (const float*)d_in[5];
    const float* v1  = (const float*)d_in[6];
    const float* w2  = (const float*)d_in[7];
    const float* b2  = (const float*)d_in[8];
    const float* g2  = (const float*)d_in[9];
    const float* be2 = (const float*)d_in[10];
    const float* m2  = (const float*)d_in[11];
    const float* v2  = (const float*)d_in[12];
    const float* w3  = (const float*)d_in[13];
    const float* b3  = (const float*)d_in[14];
    const float* g3  = (const float*)d_in[15];
    const float* be3 = (const float*)d_in[16];
    const float* m3  = (const float*)d_in[17];
    const float* v3  = (const float*)d_in[18];
    const float* wf  = (const float*)d_in[19];
    float* out = (float*)d_out;

    // d_ws: packed bf16 weights only (2.55 MB, proven safe rounds 4-19)
    unsigned short* wpack = (unsigned short*)d_ws;

    prep_weights<<<(WPACK_ELEMS + 255) / 256, 256, 0, stream>>>(w1, w2, w3, wpack);

    dim3 gridA(16, B_);   // 16 spatial tiles x 32 batch
    conv_branch<7, 0, 0><<<gridA, 512, 0, stream>>>(x, wpack, b3, g3, be3, m3, v3, out);
    conv_branch<5, 49, 1><<<gridA, 512, 0, stream>>>(x, wpack, b2, g2, be2, m2, v2, out);
    conv_branch<3, 74, 2><<<gridA, 512, 0, stream>>>(x, wpack, b1, g1, be1, m1, v1, out);

    fuse_kernel<<<B_ * D_, 256, 0, stream>>>(wf, out);
}

// Round 21
// 400.204 us; speedup vs baseline: 1.0236x; 1.0236x over previous
//
#include <hip/hip_runtime.h>
#include <hip/hip_bf16.h>

typedef __hip_bfloat16 bf16;
typedef short v8s __attribute__((ext_vector_type(8)));     // 8 bf16 (4 VGPRs)
typedef float f32x4 __attribute__((ext_vector_type(4)));   // MFMA acc
typedef unsigned int u32x4 __attribute__((ext_vector_type(4)));

#define B_  32
#define L_  144
#define D_  96
#define HW_ 64

#define PIXSTRIDE 80             // 32 l * 2B = 64B data + 16B pad (round-7/14 layout)
#define WPACK_ELEMS (83*5*96*32) // packed bf16 weights
#define ABUF_HALF 18432          // 3 taps * 6KB A per tap

__device__ __forceinline__ unsigned short f2bf(float f) {
    union { float f; unsigned int u; } x{f};
    unsigned int r = x.u + 0x7fffu + ((x.u >> 16) & 1u);   // RNE
    return (unsigned short)(r >> 16);
}
__device__ __forceinline__ float bf2f(unsigned short u) {
    union { unsigned int u; float f; } x{(unsigned int)u << 16};
    return x.f;
}

// ---------------------------------------------------------------------------
// Weight prep: pack w1/w2/w3 (fp32, [D][L][k][k]) into A-fragment order bf16:
// wpack[((T*5+q)*96 + d)*32 + l~],  T: 0..48=7x7 taps, 49..73=5x5, 74..82=3x3,
// q = l-chunk (l = q*32+l~, zero-padded past 143).  (row-major taps: round-19)
// ---------------------------------------------------------------------------
__global__ __launch_bounds__(256) void prep_weights(
    const float* __restrict__ w1, const float* __restrict__ w2,
    const float* __restrict__ w3, unsigned short* __restrict__ wpack)
{
    int i = blockIdx.x * 256 + threadIdx.x;
    if (i >= WPACK_ELEMS) return;
    const int lt = i & 31;
    const int d  = (i >> 5) % 96;
    const int r  = (i >> 5) / 96;   // T*5 + q
    const int q  = r % 5;
    const int T  = r / 5;
    const int l  = q * 32 + lt;
    float v = 0.f;
    if (l < L_) {
        if (T < 49)      v = w3[(d * L_ + l) * 49 + T];
        else if (T < 74) v = w2[(d * L_ + l) * 25 + (T - 49)];
        else             v = w1[(d * L_ + l) * 9  + (T - 74)];
    }
    wpack[i] = f2bf(v);
}

// ---------------------------------------------------------------------------
// Single-branch MFMA conv — round-19 structure VERBATIM (12 accs, VGPR 52,
// 4 waves/SIMD, [pixel][32ch] stride-80 patch, b128 staging, A-weights via
// double-buffered 3-tap-group global_load_lds) + ONE zero-register change:
// __builtin_amdgcn_s_setprio(1)/(0) around each tap's 12-MFMA cluster (T5).
// Mechanism: 2 independent blocks/CU x 8 waves in a stage->compute phase
// pipeline => wave role diversity; setprio lets MFMA-phase waves win issue
// arbitration over staging-phase waves. (Round-20's B-sharing won on
// conflicts but spilled — VGPR 64, WRITE +9MB — and regressed; reverted.)
// MODE 0: y -> slot upper half (7x7/y3); MODE 1: y -> lower (5x5/y2);
// MODE 2: y1 + combine: add -> lower, max -> upper.
// ---------------------------------------------------------------------------
template<int KSZ, int TBASE, int MODE>
__global__ __launch_bounds__(512, 4) void conv_branch(
    const float* __restrict__ x, const unsigned short* __restrict__ wpack,
    const float* __restrict__ bb, const float* __restrict__ gg,
    const float* __restrict__ bbe, const float* __restrict__ mm,
    const float* __restrict__ vv,
    float* __restrict__ outp)
{
    constexpr int PAD  = KSZ / 2;
    constexpr int PXR  = 16 + 2 * PAD;    // patch rows/cols
    constexpr int NPIX = PXR * PXR;
    constexpr int NT   = KSZ * KSZ;       // taps
    constexpr int NG   = (NT + 2) / 3;    // 3-tap groups

    __shared__ __align__(16) unsigned char patchB[NPIX * PIXSTRIDE];
    __shared__ __align__(16) unsigned char AbufRaw[2 * ABUF_HALF];
    __shared__ float bns[96 * 2];

    const int t    = threadIdx.x;
    const int lane = t & 63;
    const int wid  = t >> 6;           // 0..7
    const int dhalf = wid >> 2;        // 0..1
    const int ptb   = (wid & 3) * 4;   // px-quad base row
    const int lo = lane & 15;
    const int hi = lane >> 4;

    const int st = blockIdx.x;
    const int h0 = (st >> 2) << 4;
    const int w0 = (st & 3) << 4;
    const int b  = blockIdx.y;

    const int laneBoff = lo * PIXSTRIDE + hi * 16;

    // staging precompute: thread owns pixel t (div/mod once)
    const bool pvalid = (t < NPIX);
    const int pr = t / PXR, pc = t - pr * PXR;
    const int gh = h0 - PAD + pr, gw = w0 - PAD + pc;
    const bool inb = pvalid && ((unsigned)gh < 64u) && ((unsigned)gw < 64u);
    const float* xb = x + (((size_t)b * L_) << 12);
    const long goff = (long)(gh << 6) + gw;

    if (t < 96) {
        const float iv = gg[t] * rsqrtf(vv[t] + 1e-5f);
        bns[t*2+0] = iv;
        bns[t*2+1] = fmaf(bb[t] - mm[t], iv, bbe[t]);
    }

    f32x4 acc[3][4];
    #pragma unroll
    for (int dt = 0; dt < 3; ++dt)
        #pragma unroll
        for (int pp = 0; pp < 4; ++pp) acc[dt][pp] = (f32x4)0.f;

    // per-lane pre-swizzled A source offset (elems): lane's frag within a 512-elem block
    const int laneAsrc = (lane & 15) * 32 + (lane >> 4) * 8;

    for (int q = 0; q < 5; ++q) {
        // ---- stage patch chunk q: 4x ds_write_b128 (8 channels each) ----
        if (pvalid) {
            if (q * 32 + 31 < L_) {            // chunks 0..3: all channels valid
                #pragma unroll
                for (int l0 = 0; l0 < 32; l0 += 8) {
                    const long gbase = (long)(q * 32 + l0) * 4096 + goff;
                    const float f0 = inb ? xb[gbase]           : 0.f;
                    const float f1 = inb ? xb[gbase + 4096]    : 0.f;
                    const float f2 = inb ? xb[gbase + 2*4096]  : 0.f;
                    const float f3 = inb ? xb[gbase + 3*4096]  : 0.f;
                    const float f4 = inb ? xb[gbase + 4*4096]  : 0.f;
                    const float f5 = inb ? xb[gbase + 5*4096]  : 0.f;
                    const float f6 = inb ? xb[gbase + 6*4096]  : 0.f;
                    const float f7 = inb ? xb[gbase + 7*4096]  : 0.f;
                    const unsigned int a0 = (unsigned int)f2bf(f0) | ((unsigned int)f2bf(f1) << 16);
                    const unsigned int a1 = (unsigned int)f2bf(f2) | ((unsigned int)f2bf(f3) << 16);
                    const unsigned int a2 = (unsigned int)f2bf(f4) | ((unsigned int)f2bf(f5) << 16);
                    const unsigned int a3 = (unsigned int)f2bf(f6) | ((unsigned int)f2bf(f7) << 16);
                    const u32x4 v = {a0, a1, a2, a3};
                    *(u32x4*)(patchB + t * PIXSTRIDE + l0 * 2) = v;
                }
            } else {                           // chunk 4: channels 128..159, guard >143
                #pragma unroll
                for (int l0 = 0; l0 < 32; l0 += 8) {
                    const int lg = q * 32 + l0;
                    const long gbase = (long)lg * 4096 + goff;
                    const float f0 = (inb && lg + 0 < L_) ? xb[gbase]          : 0.f;
                    const float f1 = (inb && lg + 1 < L_) ? xb[gbase + 4096]   : 0.f;
                    const float f2 = (inb && lg + 2 < L_) ? xb[gbase + 2*4096] : 0.f;
                    const float f3 = (inb && lg + 3 < L_) ? xb[gbase + 3*4096] : 0.f;
                    const float f4 = (inb && lg + 4 < L_) ? xb[gbase + 4*4096] : 0.f;
                    const float f5 = (inb && lg + 5 < L_) ? xb[gbase + 5*4096] : 0.f;
                    const float f6 = (inb && lg + 6 < L_) ? xb[gbase + 6*4096] : 0.f;
                    const float f7 = (inb && lg + 7 < L_) ? xb[gbase + 7*4096] : 0.f;
                    const unsigned int a0 = (unsigned int)f2bf(f0) | ((unsigned int)f2bf(f1) << 16);
                    const unsigned int a1 = (unsigned int)f2bf(f2) | ((unsigned int)f2bf(f3) << 16);
                    const unsigned int a2 = (unsigned int)f2bf(f4) | ((unsigned int)f2bf(f5) << 16);
                    const unsigned int a3 = (unsigned int)f2bf(f6) | ((unsigned int)f2bf(f7) << 16);
                    const u32x4 v = {a0, a1, a2, a3};
                    *(u32x4*)(patchB + t * PIXSTRIDE + l0 * 2) = v;
                }
            }
        }

        // ---- DMA-stage A group: chunk c = tap*6 + (dhalf*3+dt), 1KB each ----
        auto stageA = [&](int tapLo, int bufOff) {
            const int rem  = NT - tapLo;
            const int nch  = (rem < 3 ? rem : 3) * 6;
            const unsigned short* gq = wpack
                + (size_t)(TBASE + tapLo) * 15360 + (size_t)q * 3072 + laneAsrc;
            for (int c = wid; c < nch; c += 8) {
                const int tapIdx = c / 6;
                const int r = c - tapIdx * 6;
                const unsigned short* g = gq + (size_t)tapIdx * 15360 + r * 512;
                __builtin_amdgcn_global_load_lds(
                    (const __attribute__((address_space(1))) unsigned int*)g,
                    (__attribute__((address_space(3))) unsigned int*)(AbufRaw + bufOff + c * 1024),
                    16, 0, 0);
            }
        };

        stageA(0, 0);          // prologue: group 0 -> buf 0
        __syncthreads();       // patch + A group 0 visible

        for (int tg = 0; tg < NG; ++tg) {
            if (tg + 1 < NG) stageA((tg + 1) * 3, ((tg + 1) & 1) * ABUF_HALF);

            // ---- compute group tg from buf[tg&1] ----
            const unsigned char* Ab = AbufRaw + (tg & 1) * ABUF_HALF;
            const int tapLo = tg * 3;
            const int rem = NT - tapLo;
            const int ntap = rem < 3 ? rem : 3;
            #pragma unroll 1
            for (int ti = 0; ti < ntap; ++ti) {
                const int tt = tapLo + ti;
                const int kh = tt / KSZ, kw = tt - kh * KSZ;
                const unsigned char* Abase = Ab + (ti * 6 + dhalf * 3) * 1024 + lane * 16;
                const v8s A0 = *(const v8s*)(Abase);
                const v8s A1 = *(const v8s*)(Abase + 1024);
                const v8s A2 = *(const v8s*)(Abase + 2048);
                const int rb0 = (ptb + kh) * PXR;
                v8s Bv[4];
                #pragma unroll
                for (int pp = 0; pp < 4; ++pp)
                    Bv[pp] = *(const v8s*)(patchB + (rb0 + pp * PXR + kw) * PIXSTRIDE + laneBoff);
                __builtin_amdgcn_s_setprio(1);
                #pragma unroll
                for (int pp = 0; pp < 4; ++pp) {
                    acc[0][pp] = __builtin_amdgcn_mfma_f32_16x16x32_bf16(A0, Bv[pp], acc[0][pp], 0, 0, 0);
                    acc[1][pp] = __builtin_amdgcn_mfma_f32_16x16x32_bf16(A1, Bv[pp], acc[1][pp], 0, 0, 0);
                    acc[2][pp] = __builtin_amdgcn_mfma_f32_16x16x32_bf16(A2, Bv[pp], acc[2][pp], 0, 0, 0);
                }
                __builtin_amdgcn_s_setprio(0);
            }
            __syncthreads();   // drains next group's DMA (covered by the 36 MFMAs above)
        }
    }

    // ---- epilogue (round-7/14 verbatim) ----
    #pragma unroll
    for (int dt = 0; dt < 3; ++dt) {
        #pragma unroll
        for (int reg = 0; reg < 4; ++reg) {
            const int d = dhalf * 48 + dt * 16 + hi * 4 + reg;
            const float iv = bns[d*2+0], cv = bns[d*2+1];
            unsigned short* pl = (unsigned short*)(outp + (((size_t)b * D_ + d) << 12));
            #pragma unroll
            for (int pp = 0; pp < 4; ++pp) {
                const float y = fmaxf(0.f, fmaf(acc[dt][pp][reg], iv, cv));
                const int idx = ((h0 + ptb + pp) << 6) + w0 + lo;
                if constexpr (MODE == 0) {
                    pl[4096 + idx] = f2bf(y);
                } else if constexpr (MODE == 1) {
                    pl[idx] = f2bf(y);
                } else {
                    const float y2 = bf2f(pl[idx]);
                    const float y3 = bf2f(pl[4096 + idx]);
                    const float av = y + y2 + y3;
                    const float mv = fmaxf(y, fmaxf(y2, y3));
                    pl[idx]        = f2bf(av);
                    pl[4096 + idx] = f2bf(mv);
                }
            }
        }
    }
}

// ---------------------------------------------------------------------------
// Kernel B: per-plane 3x3 conv over [add; max] with avg folded (unchanged).
// ---------------------------------------------------------------------------
__global__ __launch_bounds__(256) void fuse_kernel(
    const float* __restrict__ wf, float* __restrict__ out)
{
    const int p = blockIdx.x;      // plane = b*96 + d
    const int t = threadIdx.x;
    __shared__ float sa[66 * 66];
    __shared__ float sm[66 * 66];
    const bf16* base = (const bf16*)(out + ((size_t)p << 12));

    for (int i = t; i < 66 * 66; i += 256) {
        const int c = i % 66, r = i / 66;
        const int gh = r - 1, gw = c - 1;
        float va = 0.f, vm = 0.f;
        if (gh >= 0 && gh < 64 && gw >= 0 && gw < 64) {
            va = __bfloat162float(base[(gh << 6) + gw]);
            vm = __bfloat162float(base[4096 + (gh << 6) + gw]);
        }
        sa[i] = va; sm[i] = vm;
    }

    float wa[9], wm[9];
    #pragma unroll
    for (int j = 0; j < 9; ++j) {
        wa[j] = wf[j] + wf[9 + j] * (1.f / 3.f);
        wm[j] = wf[18 + j];
    }
    __syncthreads();

    float* op = out + ((size_t)p << 12);
    for (int i = t; i < 4096; i += 256) {
        const int h = i >> 6, w = i & 63;
        float acc = 0.f;
        #pragma unroll
        for (int kh = 0; kh < 3; ++kh) {
            #pragma unroll
            for (int kw = 0; kw < 3; ++kw) {
                acc = fmaf(sa[(h + kh) * 66 + (w + kw)], wa[kh * 3 + kw], acc);
                acc = fmaf(sm[(h + kh) * 66 + (w + kw)], wm[kh * 3 + kw], acc);
            }
        }
        op[i] = acc;
    }
}

extern "C" void kernel_launch(void* const* d_in, const int* in_sizes, int n_in,
                              void* d_out, int out_size, void* d_ws, size_t ws_size,
                              hipStream_t stream)
{
    const float* x   = (const float*)d_in[0];
    const float* w1  = (const float*)d_in[1];
    const float* b1  = (const float*)d_in[2];
    const float* g1  = (const float*)d_in[3];
    const float* be1 = (const float*)d_in[4];
    const float* m1  = (const float*)d_in[5];
    const float* v1  = (const float*)d_in[6];
    const float* w2  = (const float*)d_in[7];
    const float* b2  = (const float*)d_in[8];
    const float* g2  = (const float*)d_in[9];
    const float* be2 = (const float*)d_in[10];
    const float* m2  = (const float*)d_in[11];
    const float* v2  = (const float*)d_in[12];
    const float* w3  = (const float*)d_in[13];
    const float* b3  = (const float*)d_in[14];
    const float* g3  = (const float*)d_in[15];
    const float* be3 = (const float*)d_in[16];
    const float* m3  = (const float*)d_in[17];
    const float* v3  = (const float*)d_in[18];
    const float* wf  = (const float*)d_in[19];
    float* out = (float*)d_out;

    // d_ws: packed bf16 weights only (2.55 MB, proven safe rounds 4-20)
    unsigned short* wpack = (unsigned short*)d_ws;

    prep_weights<<<(WPACK_ELEMS + 255) / 256, 256, 0, stream>>>(w1, w2, w3, wpack);

    dim3 gridA(16, B_);   // 16 spatial tiles x 32 batch
    conv_branch<7, 0, 0><<<gridA, 512, 0, stream>>>(x, wpack, b3, g3, be3, m3, v3, out);
    conv_branch<5, 49, 1><<<gridA, 512, 0, stream>>>(x, wpack, b2, g2, be2, m2, v2, out);
    conv_branch<3, 74, 2><<<gridA, 512, 0, stream>>>(x, wpack, b1, g1, be1, m1, v1, out);

    fuse_kernel<<<B_ * D_, 256, 0, stream>>>(wf, out);
}

// Round 22
// 380.913 us; speedup vs baseline: 1.0754x; 1.0506x over previous
//
#include <hip/hip_runtime.h>
#include <hip/hip_bf16.h>

typedef __hip_bfloat16 bf16;
typedef short v8s __attribute__((ext_vector_type(8)));     // 8 bf16 (4 VGPRs)
typedef float f32x4 __attribute__((ext_vector_type(4)));   // MFMA acc
typedef unsigned int u32x4 __attribute__((ext_vector_type(4)));

#define B_  32
#define L_  144
#define D_  96
#define HW_ 64

#define PIXSTRIDE 80             // 32 l * 2B = 64B data + 16B pad (round-7/14 layout)
#define WPACK_ELEMS (83*5*96*32) // packed bf16 weights
#define ABUF_HALF 18432          // 3 taps * 6KB A per tap

__device__ __forceinline__ unsigned short f2bf(float f) {
    union { float f; unsigned int u; } x{f};
    unsigned int r = x.u + 0x7fffu + ((x.u >> 16) & 1u);   // RNE
    return (unsigned short)(r >> 16);
}
__device__ __forceinline__ float bf2f(unsigned short u) {
    union { unsigned int u; float f; } x{(unsigned int)u << 16};
    return x.f;
}

// ---------------------------------------------------------------------------
// Weight prep, COLUMN-MAJOR tap slots: slot T holds tap (kh = U%KSZ,
// kw = U/KSZ) of its branch (U = branch-local slot), so linear 3-tap groups
// iterate kh-inner — enabling B-row sharing within a column group.
// wpack[((T*5+q)*96 + d)*32 + l~];  T: 0..48=7x7, 49..73=5x5, 74..82=3x3.
// ---------------------------------------------------------------------------
__global__ __launch_bounds__(256) void prep_weights(
    const float* __restrict__ w1, const float* __restrict__ w2,
    const float* __restrict__ w3, unsigned short* __restrict__ wpack)
{
    int i = blockIdx.x * 256 + threadIdx.x;
    if (i >= WPACK_ELEMS) return;
    const int lt = i & 31;
    const int d  = (i >> 5) % 96;
    const int r  = (i >> 5) / 96;   // T*5 + q
    const int q  = r % 5;
    const int T  = r / 5;
    const int l  = q * 32 + lt;
    float v = 0.f;
    if (l < L_) {
        if (T < 49)      { const int U = T;      v = w3[(d * L_ + l) * 49 + (U % 7) * 7 + U / 7]; }
        else if (T < 74) { const int U = T - 49; v = w2[(d * L_ + l) * 25 + (U % 5) * 5 + U / 5]; }
        else             { const int U = T - 74; v = w1[(d * L_ + l) * 9  + (U % 3) * 3 + U / 3]; }
    }
    wpack[i] = f2bf(v);
}

// ---------------------------------------------------------------------------
// Single-branch MFMA conv — round-19 base (12 accs, 4 waves/SIMD,
// [pixel][32ch] stride-80 patch, b128 staging, A via double-buffered
// 3-tap-group global_load_lds) + round-22 change: PER-COLUMN group schedule.
// Each column of taps splits into compile-time groups (7->3,3,1; 5->3,2;
// 3->3); every group is in-column so ONE static body serves all groups:
// B window Bw[NTAP+3] read once, tap ti uses Bw[ti..ti+3]. B-reads/q:
// k7 196->112, k5 100->55, k3 36->18 (LDS-read pipe was 330K cy vs MFMA
// 228K). No dual body, no runtime-indexed vectors (round-20's spill cause).
// MODE 0: y -> slot upper half (7x7/y3); MODE 1: y -> lower (5x5/y2);
// MODE 2: y1 + combine: add -> lower, max -> upper.
// ---------------------------------------------------------------------------
template<int KSZ, int TBASE, int MODE>
__global__ __launch_bounds__(512, 4) void conv_branch(
    const float* __restrict__ x, const unsigned short* __restrict__ wpack,
    const float* __restrict__ bb, const float* __restrict__ gg,
    const float* __restrict__ bbe, const float* __restrict__ mm,
    const float* __restrict__ vv,
    float* __restrict__ outp)
{
    constexpr int PAD  = KSZ / 2;
    constexpr int PXR  = 16 + 2 * PAD;    // patch rows/cols
    constexpr int NPIX = PXR * PXR;
    constexpr int NGc  = (KSZ + 2) / 3;   // groups per column (7->3, 5->2, 3->1)
    constexpr int NG   = KSZ * NGc;       // total groups

    __shared__ __align__(16) unsigned char patchB[NPIX * PIXSTRIDE];
    __shared__ __align__(16) unsigned char AbufRaw[2 * ABUF_HALF];
    __shared__ float bns[96 * 2];

    const int t    = threadIdx.x;
    const int lane = t & 63;
    const int wid  = t >> 6;           // 0..7
    const int dhalf = wid >> 2;        // 0..1
    const int ptb   = (wid & 3) * 4;   // px-quad base row
    const int lo = lane & 15;
    const int hi = lane >> 4;

    const int st = blockIdx.x;
    const int h0 = (st >> 2) << 4;
    const int w0 = (st & 3) << 4;
    const int b  = blockIdx.y;

    const int laneBoff = lo * PIXSTRIDE + hi * 16;

    // staging precompute: thread owns pixel t (div/mod once)
    const bool pvalid = (t < NPIX);
    const int pr = t / PXR, pc = t - pr * PXR;
    const int gh = h0 - PAD + pr, gw = w0 - PAD + pc;
    const bool inb = pvalid && ((unsigned)gh < 64u) && ((unsigned)gw < 64u);
    const float* xb = x + (((size_t)b * L_) << 12);
    const long goff = (long)(gh << 6) + gw;

    if (t < 96) {
        const float iv = gg[t] * rsqrtf(vv[t] + 1e-5f);
        bns[t*2+0] = iv;
        bns[t*2+1] = fmaf(bb[t] - mm[t], iv, bbe[t]);
    }

    f32x4 acc[3][4];
    #pragma unroll
    for (int dt = 0; dt < 3; ++dt)
        #pragma unroll
        for (int pp = 0; pp < 4; ++pp) acc[dt][pp] = (f32x4)0.f;

    // per-lane pre-swizzled A source offset (elems): lane's frag within a 512-elem block
    const int laneAsrc = (lane & 15) * 32 + (lane >> 4) * 8;

    for (int q = 0; q < 5; ++q) {
        // ---- stage patch chunk q: 4x ds_write_b128 (8 channels each) ----
        if (pvalid) {
            if (q * 32 + 31 < L_) {            // chunks 0..3: all channels valid
                #pragma unroll
                for (int l0 = 0; l0 < 32; l0 += 8) {
                    const long gbase = (long)(q * 32 + l0) * 4096 + goff;
                    const float f0 = inb ? xb[gbase]           : 0.f;
                    const float f1 = inb ? xb[gbase + 4096]    : 0.f;
                    const float f2 = inb ? xb[gbase + 2*4096]  : 0.f;
                    const float f3 = inb ? xb[gbase + 3*4096]  : 0.f;
                    const float f4 = inb ? xb[gbase + 4*4096]  : 0.f;
                    const float f5 = inb ? xb[gbase + 5*4096]  : 0.f;
                    const float f6 = inb ? xb[gbase + 6*4096]  : 0.f;
                    const float f7 = inb ? xb[gbase + 7*4096]  : 0.f;
                    const unsigned int a0 = (unsigned int)f2bf(f0) | ((unsigned int)f2bf(f1) << 16);
                    const unsigned int a1 = (unsigned int)f2bf(f2) | ((unsigned int)f2bf(f3) << 16);
                    const unsigned int a2 = (unsigned int)f2bf(f4) | ((unsigned int)f2bf(f5) << 16);
                    const unsigned int a3 = (unsigned int)f2bf(f6) | ((unsigned int)f2bf(f7) << 16);
                    const u32x4 v = {a0, a1, a2, a3};
                    *(u32x4*)(patchB + t * PIXSTRIDE + l0 * 2) = v;
                }
            } else {                           // chunk 4: channels 128..159, guard >143
                #pragma unroll
                for (int l0 = 0; l0 < 32; l0 += 8) {
                    const int lg = q * 32 + l0;
                    const long gbase = (long)lg * 4096 + goff;
                    const float f0 = (inb && lg + 0 < L_) ? xb[gbase]          : 0.f;
                    const float f1 = (inb && lg + 1 < L_) ? xb[gbase + 4096]   : 0.f;
                    const float f2 = (inb && lg + 2 < L_) ? xb[gbase + 2*4096] : 0.f;
                    const float f3 = (inb && lg + 3 < L_) ? xb[gbase + 3*4096] : 0.f;
                    const float f4 = (inb && lg + 4 < L_) ? xb[gbase + 4*4096] : 0.f;
                    const float f5 = (inb && lg + 5 < L_) ? xb[gbase + 5*4096] : 0.f;
                    const float f6 = (inb && lg + 6 < L_) ? xb[gbase + 6*4096] : 0.f;
                    const float f7 = (inb && lg + 7 < L_) ? xb[gbase + 7*4096] : 0.f;
                    const unsigned int a0 = (unsigned int)f2bf(f0) | ((unsigned int)f2bf(f1) << 16);
                    const unsigned int a1 = (unsigned int)f2bf(f2) | ((unsigned int)f2bf(f3) << 16);
                    const unsigned int a2 = (unsigned int)f2bf(f4) | ((unsigned int)f2bf(f5) << 16);
                    const unsigned int a3 = (unsigned int)f2bf(f6) | ((unsigned int)f2bf(f7) << 16);
                    const u32x4 v = {a0, a1, a2, a3};
                    *(u32x4*)(patchB + t * PIXSTRIDE + l0 * 2) = v;
                }
            }
        }

        // ---- DMA-stage A group (ntap taps from tapLo), 1KB chunks ----
        auto stageA = [&](int tapLo, int ntapP, int bufOff) {
            const int nch = ntapP * 6;
            const unsigned short* gq = wpack
                + (size_t)(TBASE + tapLo) * 15360 + (size_t)q * 3072 + laneAsrc;
            for (int c = wid; c < nch; c += 8) {
                const int tapIdx = c / 6;
                const int r = c - tapIdx * 6;
                const unsigned short* g = gq + (size_t)tapIdx * 15360 + r * 512;
                __builtin_amdgcn_global_load_lds(
                    (const __attribute__((address_space(1))) unsigned int*)g,
                    (__attribute__((address_space(3))) unsigned int*)(AbufRaw + bufOff + c * 1024),
                    16, 0, 0);
            }
        };

        stageA(0, 3, 0);       // prologue: group 0 (always 3 taps) -> buf 0
        __syncthreads();       // patch + A group 0 visible

// One column group: GIDX-th group of `col` (taps kh = GIDX*3 .. GIDX*3+NTAP-1).
// B window read once (NTAP+3 rows), tap ti uses Bw[ti..ti+3]. All static.
#define PROCESS_GROUP(GIDX, NTAP)                                              \
        {                                                                      \
            const int g_ = col * NGc + (GIDX);                                 \
            const int gn_ = g_ + 1;                                            \
            if (gn_ < NG) {                                                    \
                const int coln_ = gn_ / NGc;                                   \
                const int gidxn_ = gn_ - coln_ * NGc;                          \
                const int rem_ = KSZ - gidxn_ * 3;                             \
                stageA(coln_ * KSZ + gidxn_ * 3,                               \
                       rem_ < 3 ? rem_ : 3, (gn_ & 1) * ABUF_HALF);            \
            }                                                                  \
            const unsigned char* Ab = AbufRaw + (g_ & 1) * ABUF_HALF;          \
            const int pixBase = (ptb + (GIDX) * 3) * PXR + col;                \
            v8s Bw[(NTAP) + 3];                                                \
            _Pragma("unroll")                                                  \
            for (int j = 0; j < (NTAP) + 3; ++j)                               \
                Bw[j] = *(const v8s*)(patchB + (pixBase + j * PXR) * PIXSTRIDE + laneBoff); \
            _Pragma("unroll")                                                  \
            for (int ti = 0; ti < (NTAP); ++ti) {                              \
                const unsigned char* Abase = Ab + (ti * 6 + dhalf * 3) * 1024 + lane * 16; \
                const v8s A0 = *(const v8s*)(Abase);                           \
                const v8s A1 = *(const v8s*)(Abase + 1024);                    \
                const v8s A2 = *(const v8s*)(Abase + 2048);                    \
                _Pragma("unroll")                                              \
                for (int pp = 0; pp < 4; ++pp) {                               \
                    acc[0][pp] = __builtin_amdgcn_mfma_f32_16x16x32_bf16(A0, Bw[ti + pp], acc[0][pp], 0, 0, 0); \
                    acc[1][pp] = __builtin_amdgcn_mfma_f32_16x16x32_bf16(A1, Bw[ti + pp], acc[1][pp], 0, 0, 0); \
                    acc[2][pp] = __builtin_amdgcn_mfma_f32_16x16x32_bf16(A2, Bw[ti + pp], acc[2][pp], 0, 0, 0); \
                }                                                              \
            }                                                                  \
            __syncthreads();                                                   \
        }

        #pragma unroll 1
        for (int col = 0; col < KSZ; ++col) {
            PROCESS_GROUP(0, 3)
            if constexpr (KSZ == 5) { PROCESS_GROUP(1, 2) }
            if constexpr (KSZ == 7) { PROCESS_GROUP(1, 3) PROCESS_GROUP(2, 1) }
        }
#undef PROCESS_GROUP
    }

    // ---- epilogue (round-7/14 verbatim) ----
    #pragma unroll
    for (int dt = 0; dt < 3; ++dt) {
        #pragma unroll
        for (int reg = 0; reg < 4; ++reg) {
            const int d = dhalf * 48 + dt * 16 + hi * 4 + reg;
            const float iv = bns[d*2+0], cv = bns[d*2+1];
            unsigned short* pl = (unsigned short*)(outp + (((size_t)b * D_ + d) << 12));
            #pragma unroll
            for (int pp = 0; pp < 4; ++pp) {
                const float y = fmaxf(0.f, fmaf(acc[dt][pp][reg], iv, cv));
                const int idx = ((h0 + ptb + pp) << 6) + w0 + lo;
                if constexpr (MODE == 0) {
                    pl[4096 + idx] = f2bf(y);
                } else if constexpr (MODE == 1) {
                    pl[idx] = f2bf(y);
                } else {
                    const float y2 = bf2f(pl[idx]);
                    const float y3 = bf2f(pl[4096 + idx]);
                    const float av = y + y2 + y3;
                    const float mv = fmaxf(y, fmaxf(y2, y3));
                    pl[idx]        = f2bf(av);
                    pl[4096 + idx] = f2bf(mv);
                }
            }
        }
    }
}

// ---------------------------------------------------------------------------
// Kernel B: per-plane 3x3 conv over [add; max] with avg folded (unchanged).
// ---------------------------------------------------------------------------
__global__ __launch_bounds__(256) void fuse_kernel(
    const float* __restrict__ wf, float* __restrict__ out)
{
    const int p = blockIdx.x;      // plane = b*96 + d
    const int t = threadIdx.x;
    __shared__ float sa[66 * 66];
    __shared__ float sm[66 * 66];
    const bf16* base = (const bf16*)(out + ((size_t)p << 12));

    for (int i = t; i < 66 * 66; i += 256) {
        const int c = i % 66, r = i / 66;
        const int gh = r - 1, gw = c - 1;
        float va = 0.f, vm = 0.f;
        if (gh >= 0 && gh < 64 && gw >= 0 && gw < 64) {
            va = __bfloat162float(base[(gh << 6) + gw]);
            vm = __bfloat162float(base[4096 + (gh << 6) + gw]);
        }
        sa[i] = va; sm[i] = vm;
    }

    float wa[9], wm[9];
    #pragma unroll
    for (int j = 0; j < 9; ++j) {
        wa[j] = wf[j] + wf[9 + j] * (1.f / 3.f);
        wm[j] = wf[18 + j];
    }
    __syncthreads();

    float* op = out + ((size_t)p << 12);
    for (int i = t; i < 4096; i += 256) {
        const int h = i >> 6, w = i & 63;
        float acc = 0.f;
        #pragma unroll
        for (int kh = 0; kh < 3; ++kh) {
            #pragma unroll
            for (int kw = 0; kw < 3; ++kw) {
                acc = fmaf(sa[(h + kh) * 66 + (w + kw)], wa[kh * 3 + kw], acc);
                acc = fmaf(sm[(h + kh) * 66 + (w + kw)], wm[kh * 3 + kw], acc);
            }
        }
        op[i] = acc;
    }
}

extern "C" void kernel_launch(void* const* d_in, const int* in_sizes, int n_in,
                              void* d_out, int out_size, void* d_ws, size_t ws_size,
                              hipStream_t stream)
{
    const float* x   = (const float*)d_in[0];
    const float* w1  = (const float*)d_in[1];
    const float* b1  = (const float*)d_in[2];
    const float* g1  = (const float*)d_in[3];
    const float* be1 = (const float*)d_in[4];
    const float* m1  = (const float*)d_in[5];
    const float* v1  = (const float*)d_in[6];
    const float* w2  = (const float*)d_in[7];
    const float* b2  = (const float*)d_in[8];
    const float* g2  = (const float*)d_in[9];
    const float* be2 = (const float*)d_in[10];
    const float* m2  = (const float*)d_in[11];
    const float* v2  = (const float*)d_in[12];
    const float* w3  = (const float*)d_in[13];
    const float* b3  = (const float*)d_in[14];
    const float* g3  = (const float*)d_in[15];
    const float* be3 = (const float*)d_in[16];
    const float* m3  = (const float*)d_in[17];
    const float* v3  = (const float*)d_in[18];
    const float* wf  = (const float*)d_in[19];
    float* out = (float*)d_out;

    // d_ws: packed bf16 weights only (2.55 MB, proven safe rounds 4-21)
    unsigned short* wpack = (unsigned short*)d_ws;

    prep_weights<<<(WPACK_ELEMS + 255) / 256, 256, 0, stream>>>(w1, w2, w3, wpack);

    dim3 gridA(16, B_);   // 16 spatial tiles x 32 batch
    conv_branch<7, 0, 0><<<gridA, 512, 0, stream>>>(x, wpack, b3, g3, be3, m3, v3, out);
    conv_branch<5, 49, 1><<<gridA, 512, 0, stream>>>(x, wpack, b2, g2, be2, m2, v2, out);
    conv_branch<3, 74, 2><<<gridA, 512, 0, stream>>>(x, wpack, b1, g1, be1, m1, v1, out);

    fuse_kernel<<<B_ * D_, 256, 0, stream>>>(wf, out);
}